// Round 7
// baseline (293.102 us; speedup 1.0000x reference)
//
#include <hip/hip_runtime.h>
#include <math.h>

static constexpr int B_ = 8, C_ = 512, T_ = 2048, C3_ = 1536;
static constexpr float INV_TEMP = 1.0f / 0.07f;

typedef __attribute__((ext_vector_type(8))) short short8;
typedef __attribute__((ext_vector_type(4))) float floatx4;

__device__ __forceinline__ float b2f(unsigned short u) {
  union { unsigned int i; float f; } v; v.i = ((unsigned int)u) << 16; return v.f;
}
__device__ __forceinline__ unsigned short f2b(float f) {
  union { float f; unsigned int i; } v; v.f = f;
  const unsigned int x = v.i;
  return (unsigned short)((x + 0x7FFFu + ((x >> 16) & 1u)) >> 16);
}
__device__ __forceinline__ void gld16(const unsigned short* g, unsigned short* l) {
  __builtin_amdgcn_global_load_lds(
      (const __attribute__((address_space(1))) void*)g,
      (__attribute__((address_space(3))) void*)l, 16, 0, 0);
}

// ---------------------------------------------------------------------------
// gemm_tn: proven 128x128/BK=32 TN bf16 GEMM (3-deep LDS ring, counted
// vmcnt(4) at the barrier). MODE 0: plain store. MODE 2: softmax epilogue.
// MODE 3: row divide.
// SWAP: m-tile on blockIdx.x (m-major linear order). Used for AV so the 4
// n-tiles sharing an attn A-band get ids == x (mod 8) -> same XCD -> one L2
// fill per 512 KB band instead of 4 (r6: FETCH 148 MB vs 84 ideal).
// ---------------------------------------------------------------------------
template<bool OUT_BF16, int MODE, bool SWAP = false>
__global__ __launch_bounds__(256)
void gemm_tn(const unsigned short* __restrict__ A, const unsigned short* __restrict__ B,
             void* __restrict__ Cout, int K, int lda, int ldb, int ldc,
             long long sA, long long sB, long long sC,
             const float* __restrict__ rs, const float* __restrict__ cs,
             float* __restrict__ denom, int rcStride, float scale)
{
  constexpr int NL = 4;   // gld16 per wave per tile

  const int bz = blockIdx.z;
  A += (long long)bz * sA;
  B += (long long)bz * sB;
  if (MODE == 2) { rs += (long long)bz * rcStride; cs += (long long)bz * rcStride;
                   denom += (long long)bz * rcStride; }
  if (MODE == 3) { rs += (long long)bz * rcStride; }
  const int m0 = (SWAP ? blockIdx.x : blockIdx.y) * 128;
  const int n0 = (SWAP ? blockIdx.y : blockIdx.x) * 128;
  const int tid = threadIdx.x;
  const int w = tid >> 6, lane = tid & 63;
  const int wm = (w >> 1) * 64, wn = (w & 1) * 64;
  const int rl = lane & 15, qd = lane >> 4;

  __shared__ __align__(16) unsigned short As[3][128 * 32];
  __shared__ __align__(16) unsigned short Bs[3][128 * 32];

  const int sr = lane >> 2, sg = lane & 3;
  const int ml0 = 32 * w + sr, ml1 = ml0 + 16;
  const int q0 = sg ^ ((ml0 >> 1) & 3), q1 = sg ^ ((ml1 >> 1) & 3);
  const unsigned short* gA0 = A + (long long)(m0 + ml0) * lda + q0 * 8;
  const unsigned short* gA1 = A + (long long)(m0 + ml1) * lda + q1 * 8;
  const unsigned short* gB0 = B + (long long)(n0 + ml0) * ldb + q0 * 8;
  const unsigned short* gB1 = B + (long long)(n0 + ml1) * ldb + q1 * 8;

  int aoff[4], boff[4];
  #pragma unroll
  for (int i = 0; i < 4; ++i) {
    const int mr = wm + i * 16 + rl;
    aoff[i] = mr * 32 + ((qd ^ ((mr >> 1) & 3)) * 8);
    const int nr = wn + i * 16 + rl;
    boff[i] = nr * 32 + ((qd ^ ((nr >> 1) & 3)) * 8);
  }

  floatx4 acc[4][4];
  #pragma unroll
  for (int i = 0; i < 4; ++i)
    #pragma unroll
    for (int j = 0; j < 4; ++j) acc[i][j] = 0.0f;

  auto stage = [&](int t, int bf) {
    const int ko = t * 32;
    gld16(gA0 + ko, As[bf] + (32 * w) * 32);
    gld16(gA1 + ko, As[bf] + (32 * w + 16) * 32);
    gld16(gB0 + ko, Bs[bf] + (32 * w) * 32);
    gld16(gB1 + ko, Bs[bf] + (32 * w + 16) * 32);
  };
  auto compute = [&](int bf) {
    short8 fa[4], fb[4];
    #pragma unroll
    for (int i = 0; i < 4; ++i) fa[i] = *(const short8*)(As[bf] + aoff[i]);
    #pragma unroll
    for (int j = 0; j < 4; ++j) fb[j] = *(const short8*)(Bs[bf] + boff[j]);
    #pragma unroll
    for (int i = 0; i < 4; ++i)
      #pragma unroll
      for (int j = 0; j < 4; ++j)
        acc[i][j] = __builtin_amdgcn_mfma_f32_16x16x32_bf16(fa[i], fb[j], acc[i][j], 0, 0, 0);
  };

  const int niter = K >> 5;
  stage(0, 0);
  stage(1, 1);
  int buf = 0;
  for (int i = 0; i < niter - 1; ++i) {
    asm volatile("s_waitcnt vmcnt(%0)\n\ts_barrier" :: "i"(NL) : "memory");
    if (i + 2 < niter) {
      int nb = buf + 2; if (nb >= 3) nb -= 3;
      stage(i + 2, nb);
    }
    compute(buf);
    if (++buf == 3) buf = 0;
  }
  asm volatile("s_waitcnt vmcnt(0)\n\ts_barrier" ::: "memory");
  compute(buf);

  #pragma unroll
  for (int i = 0; i < 4; ++i) {
    #pragma unroll
    for (int r = 0; r < 4; ++r) {
      const int row = m0 + wm + i * 16 + qd * 4 + r;
      float rowf = 0.f;
      if (MODE == 2) rowf = rs[row] * scale;
      if (MODE == 3) rowf = 1.0f / rs[row];
      float rsum = 0.f;
      #pragma unroll
      for (int j = 0; j < 4; ++j) {
        const int col = n0 + wn + j * 16 + rl;
        float v = acc[i][j][r];
        if (MODE == 2) {
          const float s = v * rowf * cs[col];
          const unsigned short pb = f2b(__expf(s - scale));
          rsum += b2f(pb);
          ((unsigned short*)Cout)[(long long)bz * sC + (long long)row * ldc + col] = pb;
          continue;
        }
        if (MODE == 3) v *= rowf;
        const long long idx = (long long)bz * sC + (long long)row * ldc + col;
        if (OUT_BF16) ((unsigned short*)Cout)[idx] = f2b(v);
        else          ((float*)Cout)[idx] = v;
      }
      if (MODE == 2) {
        #pragma unroll
        for (int m = 1; m < 16; m <<= 1) rsum += __shfl_xor(rsum, m);
        if (rl == 0) atomicAdd(denom + row, rsum);
      }
    }
  }
}

// ---------------------------------------------------------------------------
// gemm_tn1024: 256x256/BK=32 TN bf16 GEMM, 1024 thr = 16 waves (4x4 of
// 64x64). Same proven 3-ring + counted-vmcnt schedule as gemm_tn, but
// 4 waves/SIMD TLP. LDS = 3 x 32 KiB (dynamic). NL=2.
// ---------------------------------------------------------------------------
template<bool OUT_BF16, int MODE>
__global__ __launch_bounds__(1024)
void gemm_tn1024(const unsigned short* __restrict__ A, const unsigned short* __restrict__ B,
                 void* __restrict__ Cout, int K, int lda, int ldb, int ldc,
                 long long sA, long long sB, long long sC,
                 const float* __restrict__ rs, const float* __restrict__ cs,
                 float* __restrict__ denom, int rcStride, float scale)
{
  extern __shared__ unsigned short S[];   // [3][A 8192 | B 8192] shorts

  const int bz = blockIdx.z;
  A += (long long)bz * sA;
  B += (long long)bz * sB;
  if (MODE == 2) { rs += (long long)bz * rcStride; cs += (long long)bz * rcStride;
                   denom += (long long)bz * rcStride; }
  if (MODE == 3) { rs += (long long)bz * rcStride; }
  const int m0 = blockIdx.y * 256, n0 = blockIdx.x * 256;
  const int tid = threadIdx.x;
  const int w = tid >> 6, lane = tid & 63;
  const int wm = (w >> 2) * 64, wn = (w & 3) * 64;
  const int rl = lane & 15, qd = lane >> 4;

  const int srow = w * 16 + (lane >> 2), sg = lane & 3;
  const int qa = sg ^ ((srow >> 1) & 3);
  const unsigned short* gA = A + (long long)(m0 + srow) * lda + qa * 8;
  const unsigned short* gB = B + (long long)(n0 + srow) * ldb + qa * 8;

  const int ar = wm + rl, br = wn + rl;
  const int aoff0 = ar * 32 + ((qd ^ ((ar >> 1) & 3)) * 8);
  const int boff0 = br * 32 + ((qd ^ ((br >> 1) & 3)) * 8);

  floatx4 acc[4][4];
  #pragma unroll
  for (int i = 0; i < 4; ++i)
    #pragma unroll
    for (int j = 0; j < 4; ++j) acc[i][j] = 0.0f;

  auto stage = [&](int t, int bf) {
    const int ko = t * 32;
    gld16(gA + ko, S + bf * 16384 + w * 512);
    gld16(gB + ko, S + bf * 16384 + 8192 + w * 512);
  };
  auto compute = [&](int bf) {
    short8 fa[4], fb[4];
    const unsigned short* pA = S + bf * 16384 + aoff0;
    const unsigned short* pB = S + bf * 16384 + 8192 + boff0;
    #pragma unroll
    for (int i = 0; i < 4; ++i) fa[i] = *(const short8*)(pA + i * 512);
    #pragma unroll
    for (int j = 0; j < 4; ++j) fb[j] = *(const short8*)(pB + j * 512);
    #pragma unroll
    for (int i = 0; i < 4; ++i)
      #pragma unroll
      for (int j = 0; j < 4; ++j)
        acc[i][j] = __builtin_amdgcn_mfma_f32_16x16x32_bf16(fa[i], fb[j], acc[i][j], 0, 0, 0);
  };

  const int niter = K >> 5;
  stage(0, 0);
  stage(1, 1);
  int buf = 0;
  for (int i = 0; i < niter - 1; ++i) {
    asm volatile("s_waitcnt vmcnt(2)\n\ts_barrier" ::: "memory");
    if (i + 2 < niter) {
      int nb = buf + 2; if (nb >= 3) nb -= 3;
      stage(i + 2, nb);
    }
    compute(buf);
    if (++buf == 3) buf = 0;
  }
  asm volatile("s_waitcnt vmcnt(0)\n\ts_barrier" ::: "memory");
  compute(buf);

  #pragma unroll
  for (int i = 0; i < 4; ++i) {
    #pragma unroll
    for (int r = 0; r < 4; ++r) {
      const int row = m0 + wm + i * 16 + qd * 4 + r;
      float rowf = 0.f;
      if (MODE == 2) rowf = rs[row] * scale;
      if (MODE == 3) rowf = 1.0f / rs[row];
      float rsum = 0.f;
      #pragma unroll
      for (int j = 0; j < 4; ++j) {
        const int col = n0 + wn + j * 16 + rl;
        float v = acc[i][j][r];
        if (MODE == 2) {
          const float s = v * rowf * cs[col];
          const unsigned short pb = f2b(__expf(s - scale));
          rsum += b2f(pb);
          ((unsigned short*)Cout)[(long long)bz * sC + (long long)row * ldc + col] = pb;
          continue;
        }
        if (MODE == 3) v *= rowf;
        const long long idx = (long long)bz * sC + (long long)row * ldc + col;
        if (OUT_BF16) ((unsigned short*)Cout)[idx] = f2b(v);
        else          ((float*)Cout)[idx] = v;
      }
      if (MODE == 2) {
        #pragma unroll
        for (int m = 1; m < 16; m <<= 1) rsum += __shfl_xor(rsum, m);
        if (rl == 0) atomicAdd(denom + row, rsum);
      }
    }
  }
}

__global__ __launch_bounds__(256)
void zero_f(float* __restrict__ p, int n)
{
  const int i = blockIdx.x * 256 + threadIdx.x;
  if (i < n) p[i] = 0.f;
}

__global__ __launch_bounds__(256)
void fin_inv(float* __restrict__ p, int n)
{
  const int i = blockIdx.x * 256 + threadIdx.x;
  if (i < n) p[i] = 1.f / fmaxf(sqrtf(p[i]), 1e-12f);
}

// ---------------------------------------------------------------------------
// conv_xT: x [B,C,T] fp32 -> xT [B,T,C] bf16, VECTORIZED: 64x64 tiles,
// float4 loads, f32 LDS (65-stride, 2-way banks = free), short8 stores.
// ---------------------------------------------------------------------------
__global__ __launch_bounds__(256)
void conv_xT(const float* __restrict__ x, unsigned short* __restrict__ xT)
{
  const int b = blockIdx.z, t0 = blockIdx.x * 64, c0 = blockIdx.y * 64;
  const int tid = threadIdx.x;
  __shared__ float tile[64][65];
  const float* src = x + (long long)b * C_ * T_;
  const int cy = tid >> 2, g = tid & 3;
  const float* sp = src + (long long)(c0 + cy) * T_ + t0 + 16 * g;
  #pragma unroll
  for (int i = 0; i < 4; ++i) {
    const float4 v = *(const float4*)(sp + 4 * i);
    tile[cy][16 * g + 4 * i + 0] = v.x;
    tile[cy][16 * g + 4 * i + 1] = v.y;
    tile[cy][16 * g + 4 * i + 2] = v.z;
    tile[cy][16 * g + 4 * i + 3] = v.w;
  }
  __syncthreads();
  const int tl = tid >> 2, cg = tid & 3;
  short8 o0, o1;
  #pragma unroll
  for (int i = 0; i < 8; ++i) {
    o0[i] = (short)f2b(tile[16 * cg + i][tl]);
    o1[i] = (short)f2b(tile[16 * cg + 8 + i][tl]);
  }
  unsigned short* dst = xT + (long long)b * T_ * C_ + (long long)(t0 + tl) * C_ + c0 + 16 * cg;
  *(short8*)dst = o0;
  *(short8*)(dst + 8) = o1;
}

__global__ __launch_bounds__(256)
void conv_bf(const float* __restrict__ in, unsigned short* __restrict__ out, int n)
{
  const int i = blockIdx.x * 256 + threadIdx.x;
  if (i < n) out[i] = f2b(in[i]);
}

// ---------------------------------------------------------------------------
// dw_qkv_v2: fully-vectorized depthwise-3 for q/k/v (p = blockIdx.z%3) on
// 64t x 64c tiles of [B,3C,T] bf16. (See r6 — 81 -> out of top-5.)
// ---------------------------------------------------------------------------
__global__ __launch_bounds__(256)
void dw_qkv_v2(const unsigned short* __restrict__ qkv, const float* __restrict__ wdw,
               unsigned short* __restrict__ qT, unsigned short* __restrict__ kT,
               unsigned short* __restrict__ vout,
               float* __restrict__ sq_q, float* __restrict__ sq_k)
{
  const int bz = blockIdx.z, b = bz / 3, p = bz % 3;
  const int t0 = blockIdx.x * 64, c0 = blockIdx.y * 64;
  const int tid = threadIdx.x;
  __shared__ unsigned short tin[64][80];
  __shared__ float tout[64][65];
  const int chb = b * C3_ + p * C_;

  #pragma unroll
  for (int s = 0; s < 2; ++s) {
    const int idx = tid + s * 256;
    const int cy = idx >> 3, g = idx & 7;
    *(short8*)&tin[cy][8 + 8 * g] =
        *(const short8*)(qkv + (long long)(chb + c0 + cy) * T_ + t0 + 8 * g);
  }
  if (tid < 64) {
    tin[tid][7] = (t0 > 0) ? qkv[(long long)(chb + c0 + tid) * T_ + t0 - 1]
                           : (unsigned short)0;
  } else if (tid < 128) {
    const int cy = tid - 64;
    tin[cy][72] = (t0 + 64 < T_) ? qkv[(long long)(chb + c0 + cy) * T_ + t0 + 64]
                                 : (unsigned short)0;
  }
  __syncthreads();

  const int cy = tid >> 2, tg = tid & 3;
  const float* wp = wdw + (p * C_ + c0 + cy) * 3;
  const float w0 = wp[0], w1 = wp[1], w2 = wp[2];

  if (p == 2) {
    short8 o0, o1;
    #pragma unroll
    for (int i = 0; i < 16; ++i) {
      const int j = 16 * tg + i;
      const float v = fmaf(w0, b2f(tin[cy][7 + j]),
                      fmaf(w1, b2f(tin[cy][8 + j]), w2 * b2f(tin[cy][9 + j])));
      if (i < 8) o0[i] = (short)f2b(v); else o1[i - 8] = (short)f2b(v);
    }
    unsigned short* d = vout + (long long)(b * C_ + c0 + cy) * T_ + t0 + 16 * tg;
    *(short8*)d = o0;
    *(short8*)(d + 8) = o1;
    return;
  }

  #pragma unroll
  for (int i = 0; i < 16; ++i) {
    const int j = 16 * tg + i;
    tout[j][cy] = fmaf(w0, b2f(tin[cy][7 + j]),
                  fmaf(w1, b2f(tin[cy][8 + j]), w2 * b2f(tin[cy][9 + j])));
  }
  __syncthreads();

  unsigned short* dst = (p == 0 ? qT : kT) + (long long)b * T_ * C_;
  float* sq = (p == 0 ? sq_q : sq_k) + (long long)b * T_;
  #pragma unroll
  for (int s = 0; s < 2; ++s) {
    const int idx = tid + s * 256;
    const int tl = idx >> 3, cl = idx & 7;
    short8 o;
    float ssq = 0.f;
    #pragma unroll
    for (int i = 0; i < 8; ++i) {
      const unsigned short ub = f2b(tout[tl][8 * cl + i]);
      o[i] = (short)ub;
      const float fv = b2f(ub);
      ssq = fmaf(fv, fv, ssq);
    }
    *(short8*)(dst + (long long)(t0 + tl) * C_ + c0 + 8 * cl) = o;
    #pragma unroll
    for (int m = 1; m < 8; m <<= 1) ssq += __shfl_xor(ssq, m);
    if (cl == 0) atomicAdd(sq + t0 + tl, ssq);
  }
}

// ---------------------------------------------------------------------------
// Workspace arena (bytes), ~185.3 MB — same layout as round 0.
// ---------------------------------------------------------------------------
extern "C" void kernel_launch(void* const* d_in, const int* in_sizes, int n_in,
                              void* d_out, int out_size, void* d_ws, size_t ws_size,
                              hipStream_t stream)
{
  const float* x      = (const float*)d_in[0];
  const float* w_qkv  = (const float*)d_in[1];
  const float* w_dw   = (const float*)d_in[2];
  const float* w_proj = (const float*)d_in[3];
  float* out = (float*)d_out;

  static int attr_done = 0;
  if (!attr_done) {
    hipFuncSetAttribute((const void*)&gemm_tn1024<true, 2>,
                        hipFuncAttributeMaxDynamicSharedMemorySize, 98304);
    attr_done = 1;
  }

  char* base = (char*)d_ws;
  unsigned short* xT      = (unsigned short*)base;                    // early
  unsigned short* wqkv_bf = (unsigned short*)(base + 16777216);       // early
  unsigned short* av_t    = (unsigned short*)base;                    // late
  char* p = base + 67108864;
  unsigned short* qT = (unsigned short*)p; p += 16777216;
  unsigned short* kT = (unsigned short*)p; p += 16777216;
  unsigned short* vb = (unsigned short*)p; p += 16777216;
  unsigned short* attn   = (unsigned short*)p;
  unsigned short* qkv_bf = (unsigned short*)p;                        // early alias
  p += 67108864;
  unsigned short* wproj_bf = (unsigned short*)p; p += 524288;
  float* inv_nq = (float*)p; p += 65536;
  float* inv_nk = (float*)p; p += 65536;
  float* denom  = (float*)p;

  const long long TC = (long long)T_ * C_, TT = (long long)T_ * T_;

  // 0) conversions + zero (inv_nq | inv_nk | denom contiguous = 3*B*T floats)
  conv_xT<<<dim3(T_ / 64, C_ / 64, B_), 256, 0, stream>>>(x, xT);
  conv_bf<<<(C3_ * C_) / 256, 256, 0, stream>>>(w_qkv, wqkv_bf, C3_ * C_);
  conv_bf<<<(C_ * C_) / 256, 256, 0, stream>>>(w_proj, wproj_bf, C_ * C_);
  zero_f<<<(3 * B_ * T_) / 256, 256, 0, stream>>>(inv_nq, 3 * B_ * T_);

  // 1) qkv: 128^2 kernel, grid 1536 blocks (B-tile sharers already same-XCD)
  gemm_tn<true, 0><<<dim3(16, 12, B_), 256, 0, stream>>>(
      wqkv_bf, xT, qkv_bf, C_, C_, C_, T_,
      0LL, TC, (long long)C3_ * T_, nullptr, nullptr, nullptr, 0, 1.f);

  // 2) fused vectorized depthwise conv (q,k transposed + norm partials; v plain)
  dw_qkv_v2<<<dim3(T_ / 64, C_ / 64, B_ * 3), 256, 0, stream>>>(
      qkv_bf, w_dw, qT, kT, vb, inv_nq, inv_nk);
  fin_inv<<<(2 * B_ * T_) / 256, 256, 0, stream>>>(inv_nq, 2 * B_ * T_);

  // 3) attn: 256^2 16-wave 3-ring kernel, grid 512 = 2 clean rounds
  gemm_tn1024<true, 2><<<dim3(8, 8, B_), 1024, 98304, stream>>>(
      qT, kT, attn, C_, C_, C_, T_,
      TC, TC, TT, inv_nq, inv_nk, denom, T_, INV_TEMP);

  // 4) AV: 128^2 kernel, m-major grid (SWAP) so the 4 n-tiles sharing an
  //    attn A-band land on one XCD (ids == x mod 8) -> L2 reuse
  gemm_tn<true, 3, true><<<dim3(16, 4, B_), 256, 0, stream>>>(
      attn, vb, av_t, T_, T_, T_, C_,
      TT, (long long)C_ * T_, TC, denom, nullptr, nullptr, T_, 1.f);

  // 5) proj: 128^2 kernel, grid 512 blocks
  gemm_tn<false, 0><<<dim3(16, 4, B_), 256, 0, stream>>>(
      wproj_bf, av_t, out, C_, C_, C_, T_,
      0LL, TC, (long long)C_ * T_, nullptr, nullptr, nullptr, 0, 1.f);
}

// Round 8
// 287.360 us; speedup vs baseline: 1.0200x; 1.0200x over previous
//
#include <hip/hip_runtime.h>
#include <math.h>

static constexpr int B_ = 8, C_ = 512, T_ = 2048, C3_ = 1536;
static constexpr float INV_TEMP = 1.0f / 0.07f;

typedef __attribute__((ext_vector_type(8))) short short8;
typedef __attribute__((ext_vector_type(4))) float floatx4;

__device__ __forceinline__ float b2f(unsigned short u) {
  union { unsigned int i; float f; } v; v.i = ((unsigned int)u) << 16; return v.f;
}
__device__ __forceinline__ unsigned short f2b(float f) {
  union { float f; unsigned int i; } v; v.f = f;
  const unsigned int x = v.i;
  return (unsigned short)((x + 0x7FFFu + ((x >> 16) & 1u)) >> 16);
}
__device__ __forceinline__ void gld16(const unsigned short* g, unsigned short* l) {
  __builtin_amdgcn_global_load_lds(
      (const __attribute__((address_space(1))) void*)g,
      (__attribute__((address_space(3))) void*)l, 16, 0, 0);
}

// ---------------------------------------------------------------------------
// gemm_tn: proven 128x128/BK=32 TN bf16 GEMM (3-deep LDS ring, counted
// vmcnt(4) at the barrier). MODE 0: plain store. MODE 2: softmax epilogue.
// MODE 3: row divide.
// MAP 0: grid (nTiles, mTiles, B).  MAP 2: FLAT batch->XCD affinity — grid
// (64*B,1,1), bz = id&7 (dispatch round-robins id over XCDs, so all blocks of
// one batch share one XCD's L2; per-batch AV working set vb=2MB fits 4MB L2),
// r = id>>3, m0 = (r>>2)*128, n0 = (r&3)*128 (the 4 n-tiles sharing an attn
// A-band are consecutive in r -> temporal L2 locality for the 512KB band).
// ---------------------------------------------------------------------------
template<bool OUT_BF16, int MODE, int MAP = 0>
__global__ __launch_bounds__(256)
void gemm_tn(const unsigned short* __restrict__ A, const unsigned short* __restrict__ B,
             void* __restrict__ Cout, int K, int lda, int ldb, int ldc,
             long long sA, long long sB, long long sC,
             const float* __restrict__ rs, const float* __restrict__ cs,
             float* __restrict__ denom, int rcStride, float scale)
{
  constexpr int NL = 4;   // gld16 per wave per tile

  int bz, m0, n0;
  if (MAP == 2) {
    const int id = blockIdx.x;
    bz = id & 7;
    const int r = id >> 3;
    m0 = (r >> 2) * 128; n0 = (r & 3) * 128;
  } else {
    bz = blockIdx.z;
    m0 = blockIdx.y * 128; n0 = blockIdx.x * 128;
  }
  A += (long long)bz * sA;
  B += (long long)bz * sB;
  if (MODE == 2) { rs += (long long)bz * rcStride; cs += (long long)bz * rcStride;
                   denom += (long long)bz * rcStride; }
  if (MODE == 3) { rs += (long long)bz * rcStride; }
  const int tid = threadIdx.x;
  const int w = tid >> 6, lane = tid & 63;
  const int wm = (w >> 1) * 64, wn = (w & 1) * 64;
  const int rl = lane & 15, qd = lane >> 4;

  __shared__ __align__(16) unsigned short As[3][128 * 32];
  __shared__ __align__(16) unsigned short Bs[3][128 * 32];

  const int sr = lane >> 2, sg = lane & 3;
  const int ml0 = 32 * w + sr, ml1 = ml0 + 16;
  const int q0 = sg ^ ((ml0 >> 1) & 3), q1 = sg ^ ((ml1 >> 1) & 3);
  const unsigned short* gA0 = A + (long long)(m0 + ml0) * lda + q0 * 8;
  const unsigned short* gA1 = A + (long long)(m0 + ml1) * lda + q1 * 8;
  const unsigned short* gB0 = B + (long long)(n0 + ml0) * ldb + q0 * 8;
  const unsigned short* gB1 = B + (long long)(n0 + ml1) * ldb + q1 * 8;

  int aoff[4], boff[4];
  #pragma unroll
  for (int i = 0; i < 4; ++i) {
    const int mr = wm + i * 16 + rl;
    aoff[i] = mr * 32 + ((qd ^ ((mr >> 1) & 3)) * 8);
    const int nr = wn + i * 16 + rl;
    boff[i] = nr * 32 + ((qd ^ ((nr >> 1) & 3)) * 8);
  }

  floatx4 acc[4][4];
  #pragma unroll
  for (int i = 0; i < 4; ++i)
    #pragma unroll
    for (int j = 0; j < 4; ++j) acc[i][j] = 0.0f;

  auto stage = [&](int t, int bf) {
    const int ko = t * 32;
    gld16(gA0 + ko, As[bf] + (32 * w) * 32);
    gld16(gA1 + ko, As[bf] + (32 * w + 16) * 32);
    gld16(gB0 + ko, Bs[bf] + (32 * w) * 32);
    gld16(gB1 + ko, Bs[bf] + (32 * w + 16) * 32);
  };
  auto compute = [&](int bf) {
    short8 fa[4], fb[4];
    #pragma unroll
    for (int i = 0; i < 4; ++i) fa[i] = *(const short8*)(As[bf] + aoff[i]);
    #pragma unroll
    for (int j = 0; j < 4; ++j) fb[j] = *(const short8*)(Bs[bf] + boff[j]);
    #pragma unroll
    for (int i = 0; i < 4; ++i)
      #pragma unroll
      for (int j = 0; j < 4; ++j)
        acc[i][j] = __builtin_amdgcn_mfma_f32_16x16x32_bf16(fa[i], fb[j], acc[i][j], 0, 0, 0);
  };

  const int niter = K >> 5;
  stage(0, 0);
  stage(1, 1);
  int buf = 0;
  for (int i = 0; i < niter - 1; ++i) {
    asm volatile("s_waitcnt vmcnt(%0)\n\ts_barrier" :: "i"(NL) : "memory");
    if (i + 2 < niter) {
      int nb = buf + 2; if (nb >= 3) nb -= 3;
      stage(i + 2, nb);
    }
    compute(buf);
    if (++buf == 3) buf = 0;
  }
  asm volatile("s_waitcnt vmcnt(0)\n\ts_barrier" ::: "memory");
  compute(buf);

  #pragma unroll
  for (int i = 0; i < 4; ++i) {
    #pragma unroll
    for (int r = 0; r < 4; ++r) {
      const int row = m0 + wm + i * 16 + qd * 4 + r;
      float rowf = 0.f;
      if (MODE == 2) rowf = rs[row] * scale;
      if (MODE == 3) rowf = 1.0f / rs[row];
      float rsum = 0.f;
      #pragma unroll
      for (int j = 0; j < 4; ++j) {
        const int col = n0 + wn + j * 16 + rl;
        float v = acc[i][j][r];
        if (MODE == 2) {
          const float s = v * rowf * cs[col];
          const unsigned short pb = f2b(__expf(s - scale));
          rsum += b2f(pb);
          ((unsigned short*)Cout)[(long long)bz * sC + (long long)row * ldc + col] = pb;
          continue;
        }
        if (MODE == 3) v *= rowf;
        const long long idx = (long long)bz * sC + (long long)row * ldc + col;
        if (OUT_BF16) ((unsigned short*)Cout)[idx] = f2b(v);
        else          ((float*)Cout)[idx] = v;
      }
      if (MODE == 2) {
        #pragma unroll
        for (int m = 1; m < 16; m <<= 1) rsum += __shfl_xor(rsum, m);
        if (rl == 0) atomicAdd(denom + row, rsum);
      }
    }
  }
}

// ---------------------------------------------------------------------------
// gemm_tn1024: 256x256/BK=32 TN bf16 GEMM, 1024 thr = 16 waves (4x4 of
// 64x64). Same proven 3-ring + counted-vmcnt schedule, 4 waves/SIMD TLP.
// LDS = 3 x 32 KiB (dynamic). NL=2.
// MAP 0: grid (nT, mT, B).  MAP 1: FLAT batch->XCD affinity — grid (64*B,1,1),
// bz = id&7 so all 64 blocks of batch z land on XCD z and the batch's full
// qT+kT working set (4 MB) becomes L2-resident (r7: FETCH 75.7 MB vs 33.6
// ideal = cross-XCD thrash of 8 batches x 4 MB in each 4 MB L2).
// ---------------------------------------------------------------------------
template<bool OUT_BF16, int MODE, int MAP = 0>
__global__ __launch_bounds__(1024)
void gemm_tn1024(const unsigned short* __restrict__ A, const unsigned short* __restrict__ B,
                 void* __restrict__ Cout, int K, int lda, int ldb, int ldc,
                 long long sA, long long sB, long long sC,
                 const float* __restrict__ rs, const float* __restrict__ cs,
                 float* __restrict__ denom, int rcStride, float scale)
{
  extern __shared__ unsigned short S[];   // [3][A 8192 | B 8192] shorts

  int bz, m0, n0;
  if (MAP == 1) {
    const int id = blockIdx.x;
    bz = id & 7;
    const int r = id >> 3;
    m0 = (r >> 3) * 256; n0 = (r & 7) * 256;
  } else {
    bz = blockIdx.z;
    m0 = blockIdx.y * 256; n0 = blockIdx.x * 256;
  }
  A += (long long)bz * sA;
  B += (long long)bz * sB;
  if (MODE == 2) { rs += (long long)bz * rcStride; cs += (long long)bz * rcStride;
                   denom += (long long)bz * rcStride; }
  if (MODE == 3) { rs += (long long)bz * rcStride; }
  const int tid = threadIdx.x;
  const int w = tid >> 6, lane = tid & 63;
  const int wm = (w >> 2) * 64, wn = (w & 3) * 64;
  const int rl = lane & 15, qd = lane >> 4;

  const int srow = w * 16 + (lane >> 2), sg = lane & 3;
  const int qa = sg ^ ((srow >> 1) & 3);
  const unsigned short* gA = A + (long long)(m0 + srow) * lda + qa * 8;
  const unsigned short* gB = B + (long long)(n0 + srow) * ldb + qa * 8;

  const int ar = wm + rl, br = wn + rl;
  const int aoff0 = ar * 32 + ((qd ^ ((ar >> 1) & 3)) * 8);
  const int boff0 = br * 32 + ((qd ^ ((br >> 1) & 3)) * 8);

  floatx4 acc[4][4];
  #pragma unroll
  for (int i = 0; i < 4; ++i)
    #pragma unroll
    for (int j = 0; j < 4; ++j) acc[i][j] = 0.0f;

  auto stage = [&](int t, int bf) {
    const int ko = t * 32;
    gld16(gA + ko, S + bf * 16384 + w * 512);
    gld16(gB + ko, S + bf * 16384 + 8192 + w * 512);
  };
  auto compute = [&](int bf) {
    short8 fa[4], fb[4];
    const unsigned short* pA = S + bf * 16384 + aoff0;
    const unsigned short* pB = S + bf * 16384 + 8192 + boff0;
    #pragma unroll
    for (int i = 0; i < 4; ++i) fa[i] = *(const short8*)(pA + i * 512);
    #pragma unroll
    for (int j = 0; j < 4; ++j) fb[j] = *(const short8*)(pB + j * 512);
    #pragma unroll
    for (int i = 0; i < 4; ++i)
      #pragma unroll
      for (int j = 0; j < 4; ++j)
        acc[i][j] = __builtin_amdgcn_mfma_f32_16x16x32_bf16(fa[i], fb[j], acc[i][j], 0, 0, 0);
  };

  const int niter = K >> 5;
  stage(0, 0);
  stage(1, 1);
  int buf = 0;
  for (int i = 0; i < niter - 1; ++i) {
    asm volatile("s_waitcnt vmcnt(2)\n\ts_barrier" ::: "memory");
    if (i + 2 < niter) {
      int nb = buf + 2; if (nb >= 3) nb -= 3;
      stage(i + 2, nb);
    }
    compute(buf);
    if (++buf == 3) buf = 0;
  }
  asm volatile("s_waitcnt vmcnt(0)\n\ts_barrier" ::: "memory");
  compute(buf);

  #pragma unroll
  for (int i = 0; i < 4; ++i) {
    #pragma unroll
    for (int r = 0; r < 4; ++r) {
      const int row = m0 + wm + i * 16 + qd * 4 + r;
      float rowf = 0.f;
      if (MODE == 2) rowf = rs[row] * scale;
      if (MODE == 3) rowf = 1.0f / rs[row];
      float rsum = 0.f;
      #pragma unroll
      for (int j = 0; j < 4; ++j) {
        const int col = n0 + wn + j * 16 + rl;
        float v = acc[i][j][r];
        if (MODE == 2) {
          const float s = v * rowf * cs[col];
          const unsigned short pb = f2b(__expf(s - scale));
          rsum += b2f(pb);
          ((unsigned short*)Cout)[(long long)bz * sC + (long long)row * ldc + col] = pb;
          continue;
        }
        if (MODE == 3) v *= rowf;
        const long long idx = (long long)bz * sC + (long long)row * ldc + col;
        if (OUT_BF16) ((unsigned short*)Cout)[idx] = f2b(v);
        else          ((float*)Cout)[idx] = v;
      }
      if (MODE == 2) {
        #pragma unroll
        for (int m = 1; m < 16; m <<= 1) rsum += __shfl_xor(rsum, m);
        if (rl == 0) atomicAdd(denom + row, rsum);
      }
    }
  }
}

__global__ __launch_bounds__(256)
void zero_f(float* __restrict__ p, int n)
{
  const int i = blockIdx.x * 256 + threadIdx.x;
  if (i < n) p[i] = 0.f;
}

__global__ __launch_bounds__(256)
void fin_inv(float* __restrict__ p, int n)
{
  const int i = blockIdx.x * 256 + threadIdx.x;
  if (i < n) p[i] = 1.f / fmaxf(sqrtf(p[i]), 1e-12f);
}

// ---------------------------------------------------------------------------
// conv_xT: x [B,C,T] fp32 -> xT [B,T,C] bf16, VECTORIZED: 64x64 tiles,
// float4 loads, f32 LDS (65-stride, 2-way banks = free), short8 stores.
// ---------------------------------------------------------------------------
__global__ __launch_bounds__(256)
void conv_xT(const float* __restrict__ x, unsigned short* __restrict__ xT)
{
  const int b = blockIdx.z, t0 = blockIdx.x * 64, c0 = blockIdx.y * 64;
  const int tid = threadIdx.x;
  __shared__ float tile[64][65];
  const float* src = x + (long long)b * C_ * T_;
  const int cy = tid >> 2, g = tid & 3;
  const float* sp = src + (long long)(c0 + cy) * T_ + t0 + 16 * g;
  #pragma unroll
  for (int i = 0; i < 4; ++i) {
    const float4 v = *(const float4*)(sp + 4 * i);
    tile[cy][16 * g + 4 * i + 0] = v.x;
    tile[cy][16 * g + 4 * i + 1] = v.y;
    tile[cy][16 * g + 4 * i + 2] = v.z;
    tile[cy][16 * g + 4 * i + 3] = v.w;
  }
  __syncthreads();
  const int tl = tid >> 2, cg = tid & 3;
  short8 o0, o1;
  #pragma unroll
  for (int i = 0; i < 8; ++i) {
    o0[i] = (short)f2b(tile[16 * cg + i][tl]);
    o1[i] = (short)f2b(tile[16 * cg + 8 + i][tl]);
  }
  unsigned short* dst = xT + (long long)b * T_ * C_ + (long long)(t0 + tl) * C_ + c0 + 16 * cg;
  *(short8*)dst = o0;
  *(short8*)(dst + 8) = o1;
}

__global__ __launch_bounds__(256)
void conv_bf(const float* __restrict__ in, unsigned short* __restrict__ out, int n)
{
  const int i = blockIdx.x * 256 + threadIdx.x;
  if (i < n) out[i] = f2b(in[i]);
}

// ---------------------------------------------------------------------------
// dw_qkv_v2: fully-vectorized depthwise-3 for q/k/v (p = blockIdx.z%3) on
// 64t x 64c tiles of [B,3C,T] bf16. (See r6 — 81 -> out of top-5.)
// ---------------------------------------------------------------------------
__global__ __launch_bounds__(256)
void dw_qkv_v2(const unsigned short* __restrict__ qkv, const float* __restrict__ wdw,
               unsigned short* __restrict__ qT, unsigned short* __restrict__ kT,
               unsigned short* __restrict__ vout,
               float* __restrict__ sq_q, float* __restrict__ sq_k)
{
  const int bz = blockIdx.z, b = bz / 3, p = bz % 3;
  const int t0 = blockIdx.x * 64, c0 = blockIdx.y * 64;
  const int tid = threadIdx.x;
  __shared__ unsigned short tin[64][80];
  __shared__ float tout[64][65];
  const int chb = b * C3_ + p * C_;

  #pragma unroll
  for (int s = 0; s < 2; ++s) {
    const int idx = tid + s * 256;
    const int cy = idx >> 3, g = idx & 7;
    *(short8*)&tin[cy][8 + 8 * g] =
        *(const short8*)(qkv + (long long)(chb + c0 + cy) * T_ + t0 + 8 * g);
  }
  if (tid < 64) {
    tin[tid][7] = (t0 > 0) ? qkv[(long long)(chb + c0 + tid) * T_ + t0 - 1]
                           : (unsigned short)0;
  } else if (tid < 128) {
    const int cy = tid - 64;
    tin[cy][72] = (t0 + 64 < T_) ? qkv[(long long)(chb + c0 + cy) * T_ + t0 + 64]
                                 : (unsigned short)0;
  }
  __syncthreads();

  const int cy = tid >> 2, tg = tid & 3;
  const float* wp = wdw + (p * C_ + c0 + cy) * 3;
  const float w0 = wp[0], w1 = wp[1], w2 = wp[2];

  if (p == 2) {
    short8 o0, o1;
    #pragma unroll
    for (int i = 0; i < 16; ++i) {
      const int j = 16 * tg + i;
      const float v = fmaf(w0, b2f(tin[cy][7 + j]),
                      fmaf(w1, b2f(tin[cy][8 + j]), w2 * b2f(tin[cy][9 + j])));
      if (i < 8) o0[i] = (short)f2b(v); else o1[i - 8] = (short)f2b(v);
    }
    unsigned short* d = vout + (long long)(b * C_ + c0 + cy) * T_ + t0 + 16 * tg;
    *(short8*)d = o0;
    *(short8*)(d + 8) = o1;
    return;
  }

  #pragma unroll
  for (int i = 0; i < 16; ++i) {
    const int j = 16 * tg + i;
    tout[j][cy] = fmaf(w0, b2f(tin[cy][7 + j]),
                  fmaf(w1, b2f(tin[cy][8 + j]), w2 * b2f(tin[cy][9 + j])));
  }
  __syncthreads();

  unsigned short* dst = (p == 0 ? qT : kT) + (long long)b * T_ * C_;
  float* sq = (p == 0 ? sq_q : sq_k) + (long long)b * T_;
  #pragma unroll
  for (int s = 0; s < 2; ++s) {
    const int idx = tid + s * 256;
    const int tl = idx >> 3, cl = idx & 7;
    short8 o;
    float ssq = 0.f;
    #pragma unroll
    for (int i = 0; i < 8; ++i) {
      const unsigned short ub = f2b(tout[tl][8 * cl + i]);
      o[i] = (short)ub;
      const float fv = b2f(ub);
      ssq = fmaf(fv, fv, ssq);
    }
    *(short8*)(dst + (long long)(t0 + tl) * C_ + c0 + 8 * cl) = o;
    #pragma unroll
    for (int m = 1; m < 8; m <<= 1) ssq += __shfl_xor(ssq, m);
    if (cl == 0) atomicAdd(sq + t0 + tl, ssq);
  }
}

// ---------------------------------------------------------------------------
// Workspace arena (bytes), ~185.3 MB — same layout as round 0.
// ---------------------------------------------------------------------------
extern "C" void kernel_launch(void* const* d_in, const int* in_sizes, int n_in,
                              void* d_out, int out_size, void* d_ws, size_t ws_size,
                              hipStream_t stream)
{
  const float* x      = (const float*)d_in[0];
  const float* w_qkv  = (const float*)d_in[1];
  const float* w_dw   = (const float*)d_in[2];
  const float* w_proj = (const float*)d_in[3];
  float* out = (float*)d_out;

  static int attr_done = 0;
  if (!attr_done) {
    hipFuncSetAttribute((const void*)&gemm_tn1024<true, 2, 1>,
                        hipFuncAttributeMaxDynamicSharedMemorySize, 98304);
    attr_done = 1;
  }

  char* base = (char*)d_ws;
  unsigned short* xT      = (unsigned short*)base;                    // early
  unsigned short* wqkv_bf = (unsigned short*)(base + 16777216);       // early
  unsigned short* av_t    = (unsigned short*)base;                    // late
  char* p = base + 67108864;
  unsigned short* qT = (unsigned short*)p; p += 16777216;
  unsigned short* kT = (unsigned short*)p; p += 16777216;
  unsigned short* vb = (unsigned short*)p; p += 16777216;
  unsigned short* attn   = (unsigned short*)p;
  unsigned short* qkv_bf = (unsigned short*)p;                        // early alias
  p += 67108864;
  unsigned short* wproj_bf = (unsigned short*)p; p += 524288;
  float* inv_nq = (float*)p; p += 65536;
  float* inv_nk = (float*)p; p += 65536;
  float* denom  = (float*)p;

  const long long TC = (long long)T_ * C_, TT = (long long)T_ * T_;

  // 0) conversions + zero (inv_nq | inv_nk | denom contiguous = 3*B*T floats)
  conv_xT<<<dim3(T_ / 64, C_ / 64, B_), 256, 0, stream>>>(x, xT);
  conv_bf<<<(C3_ * C_) / 256, 256, 0, stream>>>(w_qkv, wqkv_bf, C3_ * C_);
  conv_bf<<<(C_ * C_) / 256, 256, 0, stream>>>(w_proj, wproj_bf, C_ * C_);
  zero_f<<<(3 * B_ * T_) / 256, 256, 0, stream>>>(inv_nq, 3 * B_ * T_);

  // 1) qkv: 128^2 kernel, grid 1536 blocks
  gemm_tn<true, 0><<<dim3(16, 12, B_), 256, 0, stream>>>(
      wqkv_bf, xT, qkv_bf, C_, C_, C_, T_,
      0LL, TC, (long long)C3_ * T_, nullptr, nullptr, nullptr, 0, 1.f);

  // 2) fused vectorized depthwise conv (q,k transposed + norm partials; v plain)
  dw_qkv_v2<<<dim3(T_ / 64, C_ / 64, B_ * 3), 256, 0, stream>>>(
      qkv_bf, w_dw, qT, kT, vb, inv_nq, inv_nk);
  fin_inv<<<(2 * B_ * T_) / 256, 256, 0, stream>>>(inv_nq, 2 * B_ * T_);

  // 3) attn: 256^2 16-wave kernel, FLAT batch->XCD grid (512 blocks)
  gemm_tn1024<true, 2, 1><<<dim3(64 * B_, 1, 1), 1024, 98304, stream>>>(
      qT, kT, attn, C_, C_, C_, T_,
      TC, TC, TT, inv_nq, inv_nk, denom, T_, INV_TEMP);

  // 4) AV: 128^2 kernel, FLAT batch->XCD grid (512 blocks), A-band sharers
  //    consecutive in r
  gemm_tn<true, 3, 2><<<dim3(64 * B_, 1, 1), 256, 0, stream>>>(
      attn, vb, av_t, T_, T_, T_, C_,
      TT, (long long)C_ * T_, TC, denom, nullptr, nullptr, T_, 1.f);

  // 5) proj: 128^2 kernel, grid 512 blocks
  gemm_tn<false, 0><<<dim3(16, 4, B_), 256, 0, stream>>>(
      wproj_bf, av_t, out, C_, C_, C_, T_,
      0LL, TC, (long long)C_ * T_, nullptr, nullptr, nullptr, 0, 1.f);
}

// Round 9
// 277.559 us; speedup vs baseline: 1.0560x; 1.0353x over previous
//
#include <hip/hip_runtime.h>
#include <math.h>

static constexpr int B_ = 8, C_ = 512, T_ = 2048, C3_ = 1536;
static constexpr float INV_TEMP = 1.0f / 0.07f;

typedef __attribute__((ext_vector_type(8))) short short8;
typedef __attribute__((ext_vector_type(4))) float floatx4;

__device__ __forceinline__ float b2f(unsigned short u) {
  union { unsigned int i; float f; } v; v.i = ((unsigned int)u) << 16; return v.f;
}
__device__ __forceinline__ unsigned short f2b(float f) {
  union { float f; unsigned int i; } v; v.f = f;
  const unsigned int x = v.i;
  return (unsigned short)((x + 0x7FFFu + ((x >> 16) & 1u)) >> 16);
}
__device__ __forceinline__ void gld16(const unsigned short* g, unsigned short* l) {
  __builtin_amdgcn_global_load_lds(
      (const __attribute__((address_space(1))) void*)g,
      (__attribute__((address_space(3))) void*)l, 16, 0, 0);
}

// ---------------------------------------------------------------------------
// gemm_tn: proven 128x128/BK=32 TN bf16 GEMM (3-deep LDS ring, counted
// vmcnt(4) at the barrier). MODE 0: plain store. MODE 2: softmax epilogue.
// MODE 3: row divide.
// MAP 0: grid (nTiles, mTiles, B).  MAP 2: FLAT batch->XCD affinity — grid
// (64*B,1,1), bz = id&7 (dispatch round-robins id over XCDs; per-batch AV
// working set vb=2MB fits 4MB L2), r = id>>3, m0=(r>>2)*128, n0=(r&3)*128.
// ---------------------------------------------------------------------------
template<bool OUT_BF16, int MODE, int MAP = 0>
__global__ __launch_bounds__(256)
void gemm_tn(const unsigned short* __restrict__ A, const unsigned short* __restrict__ B,
             void* __restrict__ Cout, int K, int lda, int ldb, int ldc,
             long long sA, long long sB, long long sC,
             const float* __restrict__ rs, const float* __restrict__ cs,
             float* __restrict__ denom, int rcStride, float scale)
{
  constexpr int NL = 4;   // gld16 per wave per tile

  int bz, m0, n0;
  if (MAP == 2) {
    const int id = blockIdx.x;
    bz = id & 7;
    const int r = id >> 3;
    m0 = (r >> 2) * 128; n0 = (r & 3) * 128;
  } else {
    bz = blockIdx.z;
    m0 = blockIdx.y * 128; n0 = blockIdx.x * 128;
  }
  A += (long long)bz * sA;
  B += (long long)bz * sB;
  if (MODE == 2) { rs += (long long)bz * rcStride; cs += (long long)bz * rcStride;
                   denom += (long long)bz * rcStride; }
  if (MODE == 3) { rs += (long long)bz * rcStride; }
  const int tid = threadIdx.x;
  const int w = tid >> 6, lane = tid & 63;
  const int wm = (w >> 1) * 64, wn = (w & 1) * 64;
  const int rl = lane & 15, qd = lane >> 4;

  __shared__ __align__(16) unsigned short As[3][128 * 32];
  __shared__ __align__(16) unsigned short Bs[3][128 * 32];

  const int sr = lane >> 2, sg = lane & 3;
  const int ml0 = 32 * w + sr, ml1 = ml0 + 16;
  const int q0 = sg ^ ((ml0 >> 1) & 3), q1 = sg ^ ((ml1 >> 1) & 3);
  const unsigned short* gA0 = A + (long long)(m0 + ml0) * lda + q0 * 8;
  const unsigned short* gA1 = A + (long long)(m0 + ml1) * lda + q1 * 8;
  const unsigned short* gB0 = B + (long long)(n0 + ml0) * ldb + q0 * 8;
  const unsigned short* gB1 = B + (long long)(n0 + ml1) * ldb + q1 * 8;

  int aoff[4], boff[4];
  #pragma unroll
  for (int i = 0; i < 4; ++i) {
    const int mr = wm + i * 16 + rl;
    aoff[i] = mr * 32 + ((qd ^ ((mr >> 1) & 3)) * 8);
    const int nr = wn + i * 16 + rl;
    boff[i] = nr * 32 + ((qd ^ ((nr >> 1) & 3)) * 8);
  }

  floatx4 acc[4][4];
  #pragma unroll
  for (int i = 0; i < 4; ++i)
    #pragma unroll
    for (int j = 0; j < 4; ++j) acc[i][j] = 0.0f;

  auto stage = [&](int t, int bf) {
    const int ko = t * 32;
    gld16(gA0 + ko, As[bf] + (32 * w) * 32);
    gld16(gA1 + ko, As[bf] + (32 * w + 16) * 32);
    gld16(gB0 + ko, Bs[bf] + (32 * w) * 32);
    gld16(gB1 + ko, Bs[bf] + (32 * w + 16) * 32);
  };
  auto compute = [&](int bf) {
    short8 fa[4], fb[4];
    #pragma unroll
    for (int i = 0; i < 4; ++i) fa[i] = *(const short8*)(As[bf] + aoff[i]);
    #pragma unroll
    for (int j = 0; j < 4; ++j) fb[j] = *(const short8*)(Bs[bf] + boff[j]);
    #pragma unroll
    for (int i = 0; i < 4; ++i)
      #pragma unroll
      for (int j = 0; j < 4; ++j)
        acc[i][j] = __builtin_amdgcn_mfma_f32_16x16x32_bf16(fa[i], fb[j], acc[i][j], 0, 0, 0);
  };

  const int niter = K >> 5;
  stage(0, 0);
  stage(1, 1);
  int buf = 0;
  for (int i = 0; i < niter - 1; ++i) {
    asm volatile("s_waitcnt vmcnt(%0)\n\ts_barrier" :: "i"(NL) : "memory");
    if (i + 2 < niter) {
      int nb = buf + 2; if (nb >= 3) nb -= 3;
      stage(i + 2, nb);
    }
    compute(buf);
    if (++buf == 3) buf = 0;
  }
  asm volatile("s_waitcnt vmcnt(0)\n\ts_barrier" ::: "memory");
  compute(buf);

  #pragma unroll
  for (int i = 0; i < 4; ++i) {
    #pragma unroll
    for (int r = 0; r < 4; ++r) {
      const int row = m0 + wm + i * 16 + qd * 4 + r;
      float rowf = 0.f;
      if (MODE == 2) rowf = rs[row] * scale;
      if (MODE == 3) rowf = 1.0f / rs[row];
      float rsum = 0.f;
      #pragma unroll
      for (int j = 0; j < 4; ++j) {
        const int col = n0 + wn + j * 16 + rl;
        float v = acc[i][j][r];
        if (MODE == 2) {
          const float s = v * rowf * cs[col];
          const unsigned short pb = f2b(__expf(s - scale));
          rsum += b2f(pb);
          ((unsigned short*)Cout)[(long long)bz * sC + (long long)row * ldc + col] = pb;
          continue;
        }
        if (MODE == 3) v *= rowf;
        const long long idx = (long long)bz * sC + (long long)row * ldc + col;
        if (OUT_BF16) ((unsigned short*)Cout)[idx] = f2b(v);
        else          ((float*)Cout)[idx] = v;
      }
      if (MODE == 2) {
        #pragma unroll
        for (int m = 1; m < 16; m <<= 1) rsum += __shfl_xor(rsum, m);
        if (rl == 0) atomicAdd(denom + row, rsum);
      }
    }
  }
}

// ---------------------------------------------------------------------------
// gemm_tn1024p: PERSISTENT 2-tile version of the 256x256/BK=32 16-wave GEMM
// (attn only, K=512). Grid = FLAT 256 blocks = exactly 1 block/CU, 0 tail.
// id&7 = batch (XCD affinity, r8: FETCH 75.7->25.9 MB); r=id>>3: m0=(r>>2)*256,
// n-pair base (r&3)*512. One continuous 32-iteration 3-ring K-loop: stage(t)
// uses k-offset (t&15)*32 and switches the B pointer to n+256 at t>=16 (A is
// restaged, L2-hot). Tile 1's epilogue runs after compute(15) — i.e. AFTER
// tile 2's first two stages are in flight — so tile 2's pipeline fill hides
// under tile 1's epilogue VALU (exp/stores). Ring math, per-element MFMA
// order, and two-atomics-per-row denom are identical to the split version.
// ---------------------------------------------------------------------------
template<bool OUT_BF16, int MODE>
__global__ __launch_bounds__(1024)
void gemm_tn1024p(const unsigned short* __restrict__ A, const unsigned short* __restrict__ B,
                  void* __restrict__ Cout, int K, int lda, int ldb, int ldc,
                  long long sA, long long sB, long long sC,
                  const float* __restrict__ rs, const float* __restrict__ cs,
                  float* __restrict__ denom, int rcStride, float scale)
{
  extern __shared__ unsigned short S[];   // [3][A 8192 | B 8192] shorts

  const int id = blockIdx.x;
  const int bz = id & 7;
  const int rr = id >> 3;
  const int m0 = (rr >> 2) * 256;
  const int nb = (rr & 3) * 512;          // n-pair base
  A += (long long)bz * sA;
  B += (long long)bz * sB;
  if (MODE == 2) { rs += (long long)bz * rcStride; cs += (long long)bz * rcStride;
                   denom += (long long)bz * rcStride; }
  const int tid = threadIdx.x;
  const int w = tid >> 6, lane = tid & 63;
  const int wm = (w >> 2) * 64, wn = (w & 3) * 64;
  const int rl = lane & 15, qd = lane >> 4;

  const int srow = w * 16 + (lane >> 2), sg = lane & 3;
  const int qa = sg ^ ((srow >> 1) & 3);
  const unsigned short* gA  = A + (long long)(m0 + srow) * lda + qa * 8;
  const unsigned short* gB0 = B + (long long)(nb + srow) * ldb + qa * 8;
  const unsigned short* gB1 = gB0 + (long long)256 * ldb;

  const int ar = wm + rl, br = wn + rl;
  const int aoff0 = ar * 32 + ((qd ^ ((ar >> 1) & 3)) * 8);
  const int boff0 = br * 32 + ((qd ^ ((br >> 1) & 3)) * 8);

  floatx4 acc[4][4];
  #pragma unroll
  for (int i = 0; i < 4; ++i)
    #pragma unroll
    for (int j = 0; j < 4; ++j) acc[i][j] = 0.0f;

  auto stage = [&](int t, int bf) {
    const int ko = (t & 15) * 32;
    const unsigned short* gb = (t < 16) ? gB0 : gB1;
    gld16(gA + ko, S + bf * 16384 + w * 512);
    gld16(gb + ko, S + bf * 16384 + 8192 + w * 512);
  };
  auto compute = [&](int bf) {
    short8 fa[4], fb[4];
    const unsigned short* pA = S + bf * 16384 + aoff0;
    const unsigned short* pB = S + bf * 16384 + 8192 + boff0;
    #pragma unroll
    for (int i = 0; i < 4; ++i) fa[i] = *(const short8*)(pA + i * 512);
    #pragma unroll
    for (int j = 0; j < 4; ++j) fb[j] = *(const short8*)(pB + j * 512);
    #pragma unroll
    for (int i = 0; i < 4; ++i)
      #pragma unroll
      for (int j = 0; j < 4; ++j)
        acc[i][j] = __builtin_amdgcn_mfma_f32_16x16x32_bf16(fa[i], fb[j], acc[i][j], 0, 0, 0);
  };
  auto epi = [&](int n0) {
    #pragma unroll
    for (int i = 0; i < 4; ++i) {
      #pragma unroll
      for (int r = 0; r < 4; ++r) {
        const int row = m0 + wm + i * 16 + qd * 4 + r;
        const float rowf = rs[row] * scale;
        float rsum = 0.f;
        #pragma unroll
        for (int j = 0; j < 4; ++j) {
          const int col = n0 + wn + j * 16 + rl;
          const float s = acc[i][j][r] * rowf * cs[col];
          const unsigned short pb = f2b(__expf(s - scale));
          rsum += b2f(pb);
          ((unsigned short*)Cout)[(long long)bz * sC + (long long)row * ldc + col] = pb;
        }
        #pragma unroll
        for (int m = 1; m < 16; m <<= 1) rsum += __shfl_xor(rsum, m);
        if (rl == 0) atomicAdd(denom + row, rsum);
      }
    }
    #pragma unroll
    for (int i = 0; i < 4; ++i)
      #pragma unroll
      for (int j = 0; j < 4; ++j) acc[i][j] = 0.0f;
  };

  // 32 K-iterations total (16 per n-tile), continuous 3-ring
  stage(0, 0);
  stage(1, 1);
  int buf = 0;
  for (int i = 0; i < 31; ++i) {
    asm volatile("s_waitcnt vmcnt(2)\n\ts_barrier" ::: "memory");
    if (i + 2 < 32) {
      int nbuf = buf + 2; if (nbuf >= 3) nbuf -= 3;
      stage(i + 2, nbuf);
    }
    compute(buf);
    if (i == 15) epi(nb);       // tile-1 epilogue; tile-2 stages already in flight
    if (++buf == 3) buf = 0;
  }
  asm volatile("s_waitcnt vmcnt(0)\n\ts_barrier" ::: "memory");
  compute(buf);
  epi(nb + 256);
}

__global__ __launch_bounds__(256)
void zero_f(float* __restrict__ p, int n)
{
  const int i = blockIdx.x * 256 + threadIdx.x;
  if (i < n) p[i] = 0.f;
}

__global__ __launch_bounds__(256)
void fin_inv(float* __restrict__ p, int n)
{
  const int i = blockIdx.x * 256 + threadIdx.x;
  if (i < n) p[i] = 1.f / fmaxf(sqrtf(p[i]), 1e-12f);
}

// ---------------------------------------------------------------------------
// conv_xT: x [B,C,T] fp32 -> xT [B,T,C] bf16, VECTORIZED: 64x64 tiles,
// float4 loads, f32 LDS (65-stride, 2-way banks = free), short8 stores.
// ---------------------------------------------------------------------------
__global__ __launch_bounds__(256)
void conv_xT(const float* __restrict__ x, unsigned short* __restrict__ xT)
{
  const int b = blockIdx.z, t0 = blockIdx.x * 64, c0 = blockIdx.y * 64;
  const int tid = threadIdx.x;
  __shared__ float tile[64][65];
  const float* src = x + (long long)b * C_ * T_;
  const int cy = tid >> 2, g = tid & 3;
  const float* sp = src + (long long)(c0 + cy) * T_ + t0 + 16 * g;
  #pragma unroll
  for (int i = 0; i < 4; ++i) {
    const float4 v = *(const float4*)(sp + 4 * i);
    tile[cy][16 * g + 4 * i + 0] = v.x;
    tile[cy][16 * g + 4 * i + 1] = v.y;
    tile[cy][16 * g + 4 * i + 2] = v.z;
    tile[cy][16 * g + 4 * i + 3] = v.w;
  }
  __syncthreads();
  const int tl = tid >> 2, cg = tid & 3;
  short8 o0, o1;
  #pragma unroll
  for (int i = 0; i < 8; ++i) {
    o0[i] = (short)f2b(tile[16 * cg + i][tl]);
    o1[i] = (short)f2b(tile[16 * cg + 8 + i][tl]);
  }
  unsigned short* dst = xT + (long long)b * T_ * C_ + (long long)(t0 + tl) * C_ + c0 + 16 * cg;
  *(short8*)dst = o0;
  *(short8*)(dst + 8) = o1;
}

__global__ __launch_bounds__(256)
void conv_bf(const float* __restrict__ in, unsigned short* __restrict__ out, int n)
{
  const int i = blockIdx.x * 256 + threadIdx.x;
  if (i < n) out[i] = f2b(in[i]);
}

// ---------------------------------------------------------------------------
// dw_qkv_v2: fully-vectorized depthwise-3 for q/k/v (p = blockIdx.z%3) on
// 64t x 64c tiles of [B,3C,T] bf16. (See r6 — 81 -> out of top-5.)
// ---------------------------------------------------------------------------
__global__ __launch_bounds__(256)
void dw_qkv_v2(const unsigned short* __restrict__ qkv, const float* __restrict__ wdw,
               unsigned short* __restrict__ qT, unsigned short* __restrict__ kT,
               unsigned short* __restrict__ vout,
               float* __restrict__ sq_q, float* __restrict__ sq_k)
{
  const int bz = blockIdx.z, b = bz / 3, p = bz % 3;
  const int t0 = blockIdx.x * 64, c0 = blockIdx.y * 64;
  const int tid = threadIdx.x;
  __shared__ unsigned short tin[64][80];
  __shared__ float tout[64][65];
  const int chb = b * C3_ + p * C_;

  #pragma unroll
  for (int s = 0; s < 2; ++s) {
    const int idx = tid + s * 256;
    const int cy = idx >> 3, g = idx & 7;
    *(short8*)&tin[cy][8 + 8 * g] =
        *(const short8*)(qkv + (long long)(chb + c0 + cy) * T_ + t0 + 8 * g);
  }
  if (tid < 64) {
    tin[tid][7] = (t0 > 0) ? qkv[(long long)(chb + c0 + tid) * T_ + t0 - 1]
                           : (unsigned short)0;
  } else if (tid < 128) {
    const int cy = tid - 64;
    tin[cy][72] = (t0 + 64 < T_) ? qkv[(long long)(chb + c0 + cy) * T_ + t0 + 64]
                                 : (unsigned short)0;
  }
  __syncthreads();

  const int cy = tid >> 2, tg = tid & 3;
  const float* wp = wdw + (p * C_ + c0 + cy) * 3;
  const float w0 = wp[0], w1 = wp[1], w2 = wp[2];

  if (p == 2) {
    short8 o0, o1;
    #pragma unroll
    for (int i = 0; i < 16; ++i) {
      const int j = 16 * tg + i;
      const float v = fmaf(w0, b2f(tin[cy][7 + j]),
                      fmaf(w1, b2f(tin[cy][8 + j]), w2 * b2f(tin[cy][9 + j])));
      if (i < 8) o0[i] = (short)f2b(v); else o1[i - 8] = (short)f2b(v);
    }
    unsigned short* d = vout + (long long)(b * C_ + c0 + cy) * T_ + t0 + 16 * tg;
    *(short8*)d = o0;
    *(short8*)(d + 8) = o1;
    return;
  }

  #pragma unroll
  for (int i = 0; i < 16; ++i) {
    const int j = 16 * tg + i;
    tout[j][cy] = fmaf(w0, b2f(tin[cy][7 + j]),
                  fmaf(w1, b2f(tin[cy][8 + j]), w2 * b2f(tin[cy][9 + j])));
  }
  __syncthreads();

  unsigned short* dst = (p == 0 ? qT : kT) + (long long)b * T_ * C_;
  float* sq = (p == 0 ? sq_q : sq_k) + (long long)b * T_;
  #pragma unroll
  for (int s = 0; s < 2; ++s) {
    const int idx = tid + s * 256;
    const int tl = idx >> 3, cl = idx & 7;
    short8 o;
    float ssq = 0.f;
    #pragma unroll
    for (int i = 0; i < 8; ++i) {
      const unsigned short ub = f2b(tout[tl][8 * cl + i]);
      o[i] = (short)ub;
      const float fv = b2f(ub);
      ssq = fmaf(fv, fv, ssq);
    }
    *(short8*)(dst + (long long)(t0 + tl) * C_ + c0 + 8 * cl) = o;
    #pragma unroll
    for (int m = 1; m < 8; m <<= 1) ssq += __shfl_xor(ssq, m);
    if (cl == 0) atomicAdd(sq + t0 + tl, ssq);
  }
}

// ---------------------------------------------------------------------------
// Workspace arena (bytes), ~185.3 MB — same layout as round 0.
// ---------------------------------------------------------------------------
extern "C" void kernel_launch(void* const* d_in, const int* in_sizes, int n_in,
                              void* d_out, int out_size, void* d_ws, size_t ws_size,
                              hipStream_t stream)
{
  const float* x      = (const float*)d_in[0];
  const float* w_qkv  = (const float*)d_in[1];
  const float* w_dw   = (const float*)d_in[2];
  const float* w_proj = (const float*)d_in[3];
  float* out = (float*)d_out;

  static int attr_done = 0;
  if (!attr_done) {
    hipFuncSetAttribute((const void*)&gemm_tn1024p<true, 2>,
                        hipFuncAttributeMaxDynamicSharedMemorySize, 98304);
    attr_done = 1;
  }

  char* base = (char*)d_ws;
  unsigned short* xT      = (unsigned short*)base;                    // early
  unsigned short* wqkv_bf = (unsigned short*)(base + 16777216);       // early
  unsigned short* av_t    = (unsigned short*)base;                    // late
  char* p = base + 67108864;
  unsigned short* qT = (unsigned short*)p; p += 16777216;
  unsigned short* kT = (unsigned short*)p; p += 16777216;
  unsigned short* vb = (unsigned short*)p; p += 16777216;
  unsigned short* attn   = (unsigned short*)p;
  unsigned short* qkv_bf = (unsigned short*)p;                        // early alias
  p += 67108864;
  unsigned short* wproj_bf = (unsigned short*)p; p += 524288;
  float* inv_nq = (float*)p; p += 65536;
  float* inv_nk = (float*)p; p += 65536;
  float* denom  = (float*)p;

  const long long TC = (long long)T_ * C_, TT = (long long)T_ * T_;

  // 0) conversions + zero (inv_nq | inv_nk | denom contiguous = 3*B*T floats)
  conv_xT<<<dim3(T_ / 64, C_ / 64, B_), 256, 0, stream>>>(x, xT);
  conv_bf<<<(C3_ * C_) / 256, 256, 0, stream>>>(w_qkv, wqkv_bf, C3_ * C_);
  conv_bf<<<(C_ * C_) / 256, 256, 0, stream>>>(w_proj, wproj_bf, C_ * C_);
  zero_f<<<(3 * B_ * T_) / 256, 256, 0, stream>>>(inv_nq, 3 * B_ * T_);

  // 1) qkv: 128^2 kernel, grid 1536 blocks
  gemm_tn<true, 0><<<dim3(16, 12, B_), 256, 0, stream>>>(
      wqkv_bf, xT, qkv_bf, C_, C_, C_, T_,
      0LL, TC, (long long)C3_ * T_, nullptr, nullptr, nullptr, 0, 1.f);

  // 2) fused vectorized depthwise conv (q,k transposed + norm partials; v plain)
  dw_qkv_v2<<<dim3(T_ / 64, C_ / 64, B_ * 3), 256, 0, stream>>>(
      qkv_bf, w_dw, qT, kT, vb, inv_nq, inv_nk);
  fin_inv<<<(2 * B_ * T_) / 256, 256, 0, stream>>>(inv_nq, 2 * B_ * T_);

  // 3) attn: PERSISTENT 2-tile 16-wave kernel, grid 256 = 1 block/CU, 0 tail
  gemm_tn1024p<true, 2><<<dim3(32 * B_, 1, 1), 1024, 98304, stream>>>(
      qT, kT, attn, C_, C_, C_, T_,
      TC, TC, TT, inv_nq, inv_nk, denom, T_, INV_TEMP);

  // 4) AV: 128^2 kernel, FLAT batch->XCD grid (512 blocks)
  gemm_tn<true, 3, 2><<<dim3(64 * B_, 1, 1), 256, 0, stream>>>(
      attn, vb, av_t, T_, T_, T_, C_,
      TT, (long long)C_ * T_, TC, denom, nullptr, nullptr, T_, 1.f);

  // 5) proj: 128^2 kernel, grid 512 blocks
  gemm_tn<false, 0><<<dim3(16, 4, B_), 256, 0, stream>>>(
      wproj_bf, av_t, out, C_, C_, C_, T_,
      0LL, TC, (long long)C_ * T_, nullptr, nullptr, nullptr, 0, 1.f);
}

// Round 10
// 275.819 us; speedup vs baseline: 1.0627x; 1.0063x over previous
//
#include <hip/hip_runtime.h>
#include <math.h>

static constexpr int B_ = 8, C_ = 512, T_ = 2048, C3_ = 1536;
static constexpr float INV_TEMP = 1.0f / 0.07f;

typedef __attribute__((ext_vector_type(8))) short short8;
typedef __attribute__((ext_vector_type(4))) float floatx4;

__device__ __forceinline__ float b2f(unsigned short u) {
  union { unsigned int i; float f; } v; v.i = ((unsigned int)u) << 16; return v.f;
}
__device__ __forceinline__ unsigned short f2b(float f) {
  union { float f; unsigned int i; } v; v.f = f;
  const unsigned int x = v.i;
  return (unsigned short)((x + 0x7FFFu + ((x >> 16) & 1u)) >> 16);
}
__device__ __forceinline__ void gld16(const unsigned short* g, unsigned short* l) {
  __builtin_amdgcn_global_load_lds(
      (const __attribute__((address_space(1))) void*)g,
      (__attribute__((address_space(3))) void*)l, 16, 0, 0);
}

// ---------------------------------------------------------------------------
// gemm_tn: proven 128x128/BK=32 TN bf16 GEMM (3-deep LDS ring, counted
// vmcnt(4) at the barrier). MODE 0: plain store. MODE 2: softmax epilogue.
// MODE 3: row divide.
// MAP 0: grid (nTiles, mTiles, B).  MAP 2: FLAT batch->XCD affinity — grid
// (64*B,1,1), bz = id&7 (dispatch round-robins id over XCDs; per-batch AV
// working set vb=2MB fits 4MB L2), r = id>>3, m0=(r>>2)*128, n0=(r&3)*128.
// ---------------------------------------------------------------------------
template<bool OUT_BF16, int MODE, int MAP = 0>
__global__ __launch_bounds__(256)
void gemm_tn(const unsigned short* __restrict__ A, const unsigned short* __restrict__ B,
             void* __restrict__ Cout, int K, int lda, int ldb, int ldc,
             long long sA, long long sB, long long sC,
             const float* __restrict__ rs, const float* __restrict__ cs,
             float* __restrict__ denom, int rcStride, float scale)
{
  constexpr int NL = 4;   // gld16 per wave per tile

  int bz, m0, n0;
  if (MAP == 2) {
    const int id = blockIdx.x;
    bz = id & 7;
    const int r = id >> 3;
    m0 = (r >> 2) * 128; n0 = (r & 3) * 128;
  } else {
    bz = blockIdx.z;
    m0 = blockIdx.y * 128; n0 = blockIdx.x * 128;
  }
  A += (long long)bz * sA;
  B += (long long)bz * sB;
  if (MODE == 2) { rs += (long long)bz * rcStride; cs += (long long)bz * rcStride;
                   denom += (long long)bz * rcStride; }
  if (MODE == 3) { rs += (long long)bz * rcStride; }
  const int tid = threadIdx.x;
  const int w = tid >> 6, lane = tid & 63;
  const int wm = (w >> 1) * 64, wn = (w & 1) * 64;
  const int rl = lane & 15, qd = lane >> 4;

  __shared__ __align__(16) unsigned short As[3][128 * 32];
  __shared__ __align__(16) unsigned short Bs[3][128 * 32];

  const int sr = lane >> 2, sg = lane & 3;
  const int ml0 = 32 * w + sr, ml1 = ml0 + 16;
  const int q0 = sg ^ ((ml0 >> 1) & 3), q1 = sg ^ ((ml1 >> 1) & 3);
  const unsigned short* gA0 = A + (long long)(m0 + ml0) * lda + q0 * 8;
  const unsigned short* gA1 = A + (long long)(m0 + ml1) * lda + q1 * 8;
  const unsigned short* gB0 = B + (long long)(n0 + ml0) * ldb + q0 * 8;
  const unsigned short* gB1 = B + (long long)(n0 + ml1) * ldb + q1 * 8;

  int aoff[4], boff[4];
  #pragma unroll
  for (int i = 0; i < 4; ++i) {
    const int mr = wm + i * 16 + rl;
    aoff[i] = mr * 32 + ((qd ^ ((mr >> 1) & 3)) * 8);
    const int nr = wn + i * 16 + rl;
    boff[i] = nr * 32 + ((qd ^ ((nr >> 1) & 3)) * 8);
  }

  floatx4 acc[4][4];
  #pragma unroll
  for (int i = 0; i < 4; ++i)
    #pragma unroll
    for (int j = 0; j < 4; ++j) acc[i][j] = 0.0f;

  auto stage = [&](int t, int bf) {
    const int ko = t * 32;
    gld16(gA0 + ko, As[bf] + (32 * w) * 32);
    gld16(gA1 + ko, As[bf] + (32 * w + 16) * 32);
    gld16(gB0 + ko, Bs[bf] + (32 * w) * 32);
    gld16(gB1 + ko, Bs[bf] + (32 * w + 16) * 32);
  };
  auto compute = [&](int bf) {
    short8 fa[4], fb[4];
    #pragma unroll
    for (int i = 0; i < 4; ++i) fa[i] = *(const short8*)(As[bf] + aoff[i]);
    #pragma unroll
    for (int j = 0; j < 4; ++j) fb[j] = *(const short8*)(Bs[bf] + boff[j]);
    #pragma unroll
    for (int i = 0; i < 4; ++i)
      #pragma unroll
      for (int j = 0; j < 4; ++j)
        acc[i][j] = __builtin_amdgcn_mfma_f32_16x16x32_bf16(fa[i], fb[j], acc[i][j], 0, 0, 0);
  };

  const int niter = K >> 5;
  stage(0, 0);
  stage(1, 1);
  int buf = 0;
  for (int i = 0; i < niter - 1; ++i) {
    asm volatile("s_waitcnt vmcnt(%0)\n\ts_barrier" :: "i"(NL) : "memory");
    if (i + 2 < niter) {
      int nb = buf + 2; if (nb >= 3) nb -= 3;
      stage(i + 2, nb);
    }
    compute(buf);
    if (++buf == 3) buf = 0;
  }
  asm volatile("s_waitcnt vmcnt(0)\n\ts_barrier" ::: "memory");
  compute(buf);

  #pragma unroll
  for (int i = 0; i < 4; ++i) {
    #pragma unroll
    for (int r = 0; r < 4; ++r) {
      const int row = m0 + wm + i * 16 + qd * 4 + r;
      float rowf = 0.f;
      if (MODE == 2) rowf = rs[row] * scale;
      if (MODE == 3) rowf = 1.0f / rs[row];
      float rsum = 0.f;
      #pragma unroll
      for (int j = 0; j < 4; ++j) {
        const int col = n0 + wn + j * 16 + rl;
        float v = acc[i][j][r];
        if (MODE == 2) {
          const float s = v * rowf * cs[col];
          const unsigned short pb = f2b(__expf(s - scale));
          rsum += b2f(pb);
          ((unsigned short*)Cout)[(long long)bz * sC + (long long)row * ldc + col] = pb;
          continue;
        }
        if (MODE == 3) v *= rowf;
        const long long idx = (long long)bz * sC + (long long)row * ldc + col;
        if (OUT_BF16) ((unsigned short*)Cout)[idx] = f2b(v);
        else          ((float*)Cout)[idx] = v;
      }
      if (MODE == 2) {
        #pragma unroll
        for (int m = 1; m < 16; m <<= 1) rsum += __shfl_xor(rsum, m);
        if (rl == 0) atomicAdd(denom + row, rsum);
      }
    }
  }
}

// ---------------------------------------------------------------------------
// gemm_attn8: 128x256/BK=32 TN bf16 GEMM for the attn scores+softmax step.
// 512 thr = 8 waves (2m x 4n of 64x64), 3-deep LDS ring, counted vmcnt(3)
// gate (3 gld16/thread/iter: 1 A + 2 B). LDS = 3 x (8+16) KB = 72 KB dynamic
// -> 2 BLOCKS/CU (m114: one block's barrier/vmcnt stall overlaps the other
// block's MFMA — the 16-wave/96KB version ran 1 block/CU and stalled the
// whole CU at every gate; MfmaUtil stuck at 21-25%).
// FLAT batch->XCD grid: 1024 blocks, bz=id&7 (r8: FETCH 75.7->25.9 MB),
// r=id>>3: m0=(r>>3)*128, n0=(r&7)*256.
// Epilogue = proven MODE 2 (fixed-max exp, bf16 store, denom atomics of the
// ROUNDED weights).
// ---------------------------------------------------------------------------
__global__ __launch_bounds__(512)
void gemm_attn8(const unsigned short* __restrict__ A, const unsigned short* __restrict__ B,
                unsigned short* __restrict__ Cout, int K, int lda, int ldb, int ldc,
                long long sA, long long sB, long long sC,
                const float* __restrict__ rs, const float* __restrict__ cs,
                float* __restrict__ denom, int rcStride, float scale)
{
  extern __shared__ unsigned short S[];   // As: 3 x 4096 shorts | Bs: 3 x 8192

  const int id = blockIdx.x;
  const int bz = id & 7;
  const int r = id >> 3;
  const int m0 = (r >> 3) * 128, n0 = (r & 7) * 256;
  A += (long long)bz * sA;
  B += (long long)bz * sB;
  rs += (long long)bz * rcStride; cs += (long long)bz * rcStride;
  denom += (long long)bz * rcStride;
  const int tid = threadIdx.x;
  const int w = tid >> 6, lane = tid & 63;
  const int wm = (w >> 2) * 64, wn = (w & 3) * 64;
  const int rl = lane & 15, qd = lane >> 4;

  // staging: A rows 0..127 (tid>>2), B rows in 2 passes of 128; granule
  // slot tid&3, global granule XOR-swizzled (proven pattern).
  const int srw = tid >> 2, sg = tid & 3;
  const int qa  = sg ^ ((srw >> 1) & 3);
  const int brw1 = 128 + srw;
  const int qb1 = sg ^ ((brw1 >> 1) & 3);
  const unsigned short* gA  = A + (long long)(m0 + srw) * lda + qa * 8;
  const unsigned short* gB0 = B + (long long)(n0 + srw) * ldb + qa * 8;   // row<128: same swz as A
  const unsigned short* gB1 = B + (long long)(n0 + brw1) * ldb + qb1 * 8;
  unsigned short* dA  = S + srw * 32 + sg * 8;
  unsigned short* dB0 = S + 12288 + srw * 32 + sg * 8;
  unsigned short* dB1 = S + 12288 + brw1 * 32 + sg * 8;

  int aoff[4], boff[4];
  #pragma unroll
  for (int i = 0; i < 4; ++i) {
    const int mr = wm + i * 16 + rl;
    aoff[i] = mr * 32 + ((qd ^ ((mr >> 1) & 3)) * 8);
    const int nr = wn + i * 16 + rl;
    boff[i] = 12288 + nr * 32 + ((qd ^ ((nr >> 1) & 3)) * 8);
  }

  floatx4 acc[4][4];
  #pragma unroll
  for (int i = 0; i < 4; ++i)
    #pragma unroll
    for (int j = 0; j < 4; ++j) acc[i][j] = 0.0f;

  auto stage = [&](int t, int bf) {
    const int ko = t * 32;
    gld16(gA + ko,  dA  + bf * 4096);
    gld16(gB0 + ko, dB0 + bf * 8192);
    gld16(gB1 + ko, dB1 + bf * 8192);
  };
  auto compute = [&](int bf) {
    short8 fa[4], fb[4];
    const unsigned short* pA = S + bf * 4096;
    const unsigned short* pB = S + bf * 8192;   // boff already includes +12288
    #pragma unroll
    for (int i = 0; i < 4; ++i) fa[i] = *(const short8*)(pA + aoff[i]);
    #pragma unroll
    for (int j = 0; j < 4; ++j) fb[j] = *(const short8*)(pB + boff[j]);
    #pragma unroll
    for (int i = 0; i < 4; ++i)
      #pragma unroll
      for (int j = 0; j < 4; ++j)
        acc[i][j] = __builtin_amdgcn_mfma_f32_16x16x32_bf16(fa[i], fb[j], acc[i][j], 0, 0, 0);
  };

  const int niter = K >> 5;   // 16
  stage(0, 0);
  stage(1, 1);
  int buf = 0;
  for (int i = 0; i < niter - 1; ++i) {
    asm volatile("s_waitcnt vmcnt(3)\n\ts_barrier" ::: "memory");
    if (i + 2 < niter) {
      int nb = buf + 2; if (nb >= 3) nb -= 3;
      stage(i + 2, nb);
    }
    compute(buf);
    if (++buf == 3) buf = 0;
  }
  asm volatile("s_waitcnt vmcnt(0)\n\ts_barrier" ::: "memory");
  compute(buf);

  float cf4[4];
  #pragma unroll
  for (int j = 0; j < 4; ++j) cf4[j] = cs[n0 + wn + j * 16 + rl];
  #pragma unroll
  for (int i = 0; i < 4; ++i) {
    #pragma unroll
    for (int rr = 0; rr < 4; ++rr) {
      const int row = m0 + wm + i * 16 + qd * 4 + rr;
      const float rowf = rs[row] * scale;
      float rsum = 0.f;
      #pragma unroll
      for (int j = 0; j < 4; ++j) {
        const int col = n0 + wn + j * 16 + rl;
        const float s = acc[i][j][rr] * rowf * cf4[j];
        const unsigned short pb = f2b(__expf(s - scale));
        rsum += b2f(pb);
        Cout[(long long)bz * sC + (long long)row * ldc + col] = pb;
      }
      #pragma unroll
      for (int m = 1; m < 16; m <<= 1) rsum += __shfl_xor(rsum, m);
      if (rl == 0) atomicAdd(denom + row, rsum);
    }
  }
}

__global__ __launch_bounds__(256)
void zero_f(float* __restrict__ p, int n)
{
  const int i = blockIdx.x * 256 + threadIdx.x;
  if (i < n) p[i] = 0.f;
}

__global__ __launch_bounds__(256)
void fin_inv(float* __restrict__ p, int n)
{
  const int i = blockIdx.x * 256 + threadIdx.x;
  if (i < n) p[i] = 1.f / fmaxf(sqrtf(p[i]), 1e-12f);
}

// ---------------------------------------------------------------------------
// conv_xT: x [B,C,T] fp32 -> xT [B,T,C] bf16, VECTORIZED: 64x64 tiles,
// float4 loads, f32 LDS (65-stride, 2-way banks = free), short8 stores.
// ---------------------------------------------------------------------------
__global__ __launch_bounds__(256)
void conv_xT(const float* __restrict__ x, unsigned short* __restrict__ xT)
{
  const int b = blockIdx.z, t0 = blockIdx.x * 64, c0 = blockIdx.y * 64;
  const int tid = threadIdx.x;
  __shared__ float tile[64][65];
  const float* src = x + (long long)b * C_ * T_;
  const int cy = tid >> 2, g = tid & 3;
  const float* sp = src + (long long)(c0 + cy) * T_ + t0 + 16 * g;
  #pragma unroll
  for (int i = 0; i < 4; ++i) {
    const float4 v = *(const float4*)(sp + 4 * i);
    tile[cy][16 * g + 4 * i + 0] = v.x;
    tile[cy][16 * g + 4 * i + 1] = v.y;
    tile[cy][16 * g + 4 * i + 2] = v.z;
    tile[cy][16 * g + 4 * i + 3] = v.w;
  }
  __syncthreads();
  const int tl = tid >> 2, cg = tid & 3;
  short8 o0, o1;
  #pragma unroll
  for (int i = 0; i < 8; ++i) {
    o0[i] = (short)f2b(tile[16 * cg + i][tl]);
    o1[i] = (short)f2b(tile[16 * cg + 8 + i][tl]);
  }
  unsigned short* dst = xT + (long long)b * T_ * C_ + (long long)(t0 + tl) * C_ + c0 + 16 * cg;
  *(short8*)dst = o0;
  *(short8*)(dst + 8) = o1;
}

__global__ __launch_bounds__(256)
void conv_bf(const float* __restrict__ in, unsigned short* __restrict__ out, int n)
{
  const int i = blockIdx.x * 256 + threadIdx.x;
  if (i < n) out[i] = f2b(in[i]);
}

// ---------------------------------------------------------------------------
// dw_qkv_v2: fully-vectorized depthwise-3 for q/k/v (p = blockIdx.z%3) on
// 64t x 64c tiles of [B,3C,T] bf16. (See r6 — 81 -> out of top-5.)
// ---------------------------------------------------------------------------
__global__ __launch_bounds__(256)
void dw_qkv_v2(const unsigned short* __restrict__ qkv, const float* __restrict__ wdw,
               unsigned short* __restrict__ qT, unsigned short* __restrict__ kT,
               unsigned short* __restrict__ vout,
               float* __restrict__ sq_q, float* __restrict__ sq_k)
{
  const int bz = blockIdx.z, b = bz / 3, p = bz % 3;
  const int t0 = blockIdx.x * 64, c0 = blockIdx.y * 64;
  const int tid = threadIdx.x;
  __shared__ unsigned short tin[64][80];
  __shared__ float tout[64][65];
  const int chb = b * C3_ + p * C_;

  #pragma unroll
  for (int s = 0; s < 2; ++s) {
    const int idx = tid + s * 256;
    const int cy = idx >> 3, g = idx & 7;
    *(short8*)&tin[cy][8 + 8 * g] =
        *(const short8*)(qkv + (long long)(chb + c0 + cy) * T_ + t0 + 8 * g);
  }
  if (tid < 64) {
    tin[tid][7] = (t0 > 0) ? qkv[(long long)(chb + c0 + tid) * T_ + t0 - 1]
                           : (unsigned short)0;
  } else if (tid < 128) {
    const int cy = tid - 64;
    tin[cy][72] = (t0 + 64 < T_) ? qkv[(long long)(chb + c0 + cy) * T_ + t0 + 64]
                                 : (unsigned short)0;
  }
  __syncthreads();

  const int cy = tid >> 2, tg = tid & 3;
  const float* wp = wdw + (p * C_ + c0 + cy) * 3;
  const float w0 = wp[0], w1 = wp[1], w2 = wp[2];

  if (p == 2) {
    short8 o0, o1;
    #pragma unroll
    for (int i = 0; i < 16; ++i) {
      const int j = 16 * tg + i;
      const float v = fmaf(w0, b2f(tin[cy][7 + j]),
                      fmaf(w1, b2f(tin[cy][8 + j]), w2 * b2f(tin[cy][9 + j])));
      if (i < 8) o0[i] = (short)f2b(v); else o1[i - 8] = (short)f2b(v);
    }
    unsigned short* d = vout + (long long)(b * C_ + c0 + cy) * T_ + t0 + 16 * tg;
    *(short8*)d = o0;
    *(short8*)(d + 8) = o1;
    return;
  }

  #pragma unroll
  for (int i = 0; i < 16; ++i) {
    const int j = 16 * tg + i;
    tout[j][cy] = fmaf(w0, b2f(tin[cy][7 + j]),
                  fmaf(w1, b2f(tin[cy][8 + j]), w2 * b2f(tin[cy][9 + j])));
  }
  __syncthreads();

  unsigned short* dst = (p == 0 ? qT : kT) + (long long)b * T_ * C_;
  float* sq = (p == 0 ? sq_q : sq_k) + (long long)b * T_;
  #pragma unroll
  for (int s = 0; s < 2; ++s) {
    const int idx = tid + s * 256;
    const int tl = idx >> 3, cl = idx & 7;
    short8 o;
    float ssq = 0.f;
    #pragma unroll
    for (int i = 0; i < 8; ++i) {
      const unsigned short ub = f2b(tout[tl][8 * cl + i]);
      o[i] = (short)ub;
      const float fv = b2f(ub);
      ssq = fmaf(fv, fv, ssq);
    }
    *(short8*)(dst + (long long)(t0 + tl) * C_ + c0 + 8 * cl) = o;
    #pragma unroll
    for (int m = 1; m < 8; m <<= 1) ssq += __shfl_xor(ssq, m);
    if (cl == 0) atomicAdd(sq + t0 + tl, ssq);
  }
}

// ---------------------------------------------------------------------------
// Workspace arena (bytes), ~185.3 MB — same layout as round 0.
// ---------------------------------------------------------------------------
extern "C" void kernel_launch(void* const* d_in, const int* in_sizes, int n_in,
                              void* d_out, int out_size, void* d_ws, size_t ws_size,
                              hipStream_t stream)
{
  const float* x      = (const float*)d_in[0];
  const float* w_qkv  = (const float*)d_in[1];
  const float* w_dw   = (const float*)d_in[2];
  const float* w_proj = (const float*)d_in[3];
  float* out = (float*)d_out;

  static int attr_done = 0;
  if (!attr_done) {
    hipFuncSetAttribute((const void*)&gemm_attn8,
                        hipFuncAttributeMaxDynamicSharedMemorySize, 73728);
    attr_done = 1;
  }

  char* base = (char*)d_ws;
  unsigned short* xT      = (unsigned short*)base;                    // early
  unsigned short* wqkv_bf = (unsigned short*)(base + 16777216);       // early
  unsigned short* av_t    = (unsigned short*)base;                    // late
  char* p = base + 67108864;
  unsigned short* qT = (unsigned short*)p; p += 16777216;
  unsigned short* kT = (unsigned short*)p; p += 16777216;
  unsigned short* vb = (unsigned short*)p; p += 16777216;
  unsigned short* attn   = (unsigned short*)p;
  unsigned short* qkv_bf = (unsigned short*)p;                        // early alias
  p += 67108864;
  unsigned short* wproj_bf = (unsigned short*)p; p += 524288;
  float* inv_nq = (float*)p; p += 65536;
  float* inv_nk = (float*)p; p += 65536;
  float* denom  = (float*)p;

  const long long TC = (long long)T_ * C_, TT = (long long)T_ * T_;

  // 0) conversions + zero (inv_nq | inv_nk | denom contiguous = 3*B*T floats)
  conv_xT<<<dim3(T_ / 64, C_ / 64, B_), 256, 0, stream>>>(x, xT);
  conv_bf<<<(C3_ * C_) / 256, 256, 0, stream>>>(w_qkv, wqkv_bf, C3_ * C_);
  conv_bf<<<(C_ * C_) / 256, 256, 0, stream>>>(w_proj, wproj_bf, C_ * C_);
  zero_f<<<(3 * B_ * T_) / 256, 256, 0, stream>>>(inv_nq, 3 * B_ * T_);

  // 1) qkv: 128^2 kernel, grid 1536 blocks
  gemm_tn<true, 0><<<dim3(16, 12, B_), 256, 0, stream>>>(
      wqkv_bf, xT, qkv_bf, C_, C_, C_, T_,
      0LL, TC, (long long)C3_ * T_, nullptr, nullptr, nullptr, 0, 1.f);

  // 2) fused vectorized depthwise conv (q,k transposed + norm partials; v plain)
  dw_qkv_v2<<<dim3(T_ / 64, C_ / 64, B_ * 3), 256, 0, stream>>>(
      qkv_bf, w_dw, qT, kT, vb, inv_nq, inv_nk);
  fin_inv<<<(2 * B_ * T_) / 256, 256, 0, stream>>>(inv_nq, 2 * B_ * T_);

  // 3) attn: 8-wave 128x256 kernel, 72 KB LDS -> 2 blocks/CU, flat
  //    batch->XCD grid (1024 blocks)
  gemm_attn8<<<dim3(128 * B_, 1, 1), 512, 73728, stream>>>(
      qT, kT, attn, C_, C_, C_, T_,
      TC, TC, TT, inv_nq, inv_nk, denom, T_, INV_TEMP);

  // 4) AV: 128^2 kernel, FLAT batch->XCD grid (512 blocks)
  gemm_tn<true, 3, 2><<<dim3(64 * B_, 1, 1), 256, 0, stream>>>(
      attn, vb, av_t, T_, T_, T_, C_,
      TT, (long long)C_ * T_, TC, denom, nullptr, nullptr, T_, 1.f);

  // 5) proj: 128^2 kernel, grid 512 blocks
  gemm_tn<false, 0><<<dim3(16, 4, B_), 256, 0, stream>>>(
      wproj_bf, av_t, out, C_, C_, C_, T_,
      0LL, TC, (long long)C_ * T_, nullptr, nullptr, nullptr, 0, 1.f);
}